// Round 4
// baseline (176.259 us; speedup 1.0000x reference)
//
#include <hip/hip_runtime.h>
#include <stdint.h>

typedef _Float16 f16;
typedef f16 f16x8 __attribute__((ext_vector_type(8)));
typedef float f32x4 __attribute__((ext_vector_type(4)));

#define NUM_NODES 20000
#define NUM_EDGES 65536
#define WIDTH 64
#define EDGE_FEAT 6
#define HIDDEN 128
#define BM 128            // edges per workgroup (full-K, grid 512, 2 blk/CU)
#define NCHUNK 129        // 128 h-chunks + 1 bias chunk (h==1)
#define XPAD 72           // x-tile row stride in halfs

#define XH_HALFS (NUM_NODES * WIDTH)   // 1,280,000 halfs for x in f16
#define XCONV_BLKS 625                 // 625 * 2048 halfs = 1,280,000 exactly
#define W2G_HALFS (NCHUNK * 4096)      // 528,384 halfs
#define HT_HALFS ((size_t)NCHUNK * NUM_EDGES)  // 8,454,144 halfs (16.9 MB)
#define HBLKS (NUM_EDGES / 256)        // 256 h-precompute blocks
#define OUT_FLOATS (NUM_NODES * WIDTH) // 1,280,000
#define ZBLKS 313                      // 313 * 4096 >= OUT_FLOATS

// direct global->LDS DMA, 16B per lane. lds dest wave-uniform; HW adds lane*16.
__device__ __forceinline__ void gload_lds16(const f16* g, f16* l) {
  __builtin_amdgcn_global_load_lds(
      (const __attribute__((address_space(1))) unsigned int*)g,
      (__attribute__((address_space(3))) unsigned int*)l, 16, 0, 0);
}

// ---------------------------------------------------------------------------
// Prep: (a) W2g swizzled f16 chunks; (b) x fp32->f16; (c) zero out;
//       (d) h_T[129][E] f16 (bias row = 1).
// ---------------------------------------------------------------------------
__global__ __launch_bounds__(256) void prep_kernel(
    const float* __restrict__ x, const float* __restrict__ W2,
    const float* __restrict__ b2, const float* __restrict__ ea,
    const float* __restrict__ W1, const float* __restrict__ b1,
    f16* __restrict__ ws_h, float* __restrict__ out, int use_ht)
{
  f16* x_h = ws_h;
  f16* W2g = ws_h + XH_HALFS;
  f16* hT  = ws_h + XH_HALFS + W2G_HALFS;
  const int blk = blockIdx.x, tid = threadIdx.x;

  if (blk < NCHUNK) {
    __shared__ float row[4096];
    const int ki = blk;
    const float* srcrow;
    if (ki < HIDDEN) {
      const float4* src = (const float4*)(W2 + (size_t)ki * 4096);
      #pragma unroll
      for (int i = 0; i < 4; ++i) {
        float4 v = src[tid + 256 * i];
        *(float4*)&row[(tid + 256 * i) * 4] = v;
      }
      __syncthreads();
      srcrow = row;
    } else {
      srcrow = b2;  // bias chunk
    }
    const int obase = tid * 16;
    f16x8 outv0, outv1;
    #pragma unroll
    for (int u = 0; u < 8; ++u) {
      int o = obase + u;
      int n = o >> 6, pg = (o >> 3) & 7, j = o & 7;
      int k = (pg ^ (n & 7)) * 8 + j;
      outv0[u] = (f16)srcrow[k * 64 + n];
    }
    #pragma unroll
    for (int u = 0; u < 8; ++u) {
      int o = obase + 8 + u;
      int n = o >> 6, pg = (o >> 3) & 7, j = o & 7;
      int k = (pg ^ (n & 7)) * 8 + j;
      outv1[u] = (f16)srcrow[k * 64 + n];
    }
    *(f16x8*)&W2g[(size_t)ki * 4096 + obase] = outv0;
    *(f16x8*)&W2g[(size_t)ki * 4096 + obase + 8] = outv1;
  } else if (blk < NCHUNK + XCONV_BLKS) {
    int idx = (blk - NCHUNK) * 2048 + tid * 8;
    if (idx + 8 <= XH_HALFS) {
      float4 a = *(const float4*)(x + idx);
      float4 b = *(const float4*)(x + idx + 4);
      f16x8 hv;
      hv[0] = (f16)a.x; hv[1] = (f16)a.y; hv[2] = (f16)a.z; hv[3] = (f16)a.w;
      hv[4] = (f16)b.x; hv[5] = (f16)b.y; hv[6] = (f16)b.z; hv[7] = (f16)b.w;
      *(f16x8*)&x_h[idx] = hv;
    }
  } else if (blk < NCHUNK + XCONV_BLKS + ZBLKS) {
    int base = (blk - NCHUNK - XCONV_BLKS) * 4096 + tid * 16;
    float4 z = {0.f, 0.f, 0.f, 0.f};
    #pragma unroll
    for (int i = 0; i < 4; ++i) {
      int idx = base + i * 4;
      if (idx + 4 <= OUT_FLOATS) *(float4*)(out + idx) = z;
    }
  } else if (use_ht) {
    __shared__ float w1s[EDGE_FEAT * HIDDEN];
    __shared__ float b1s[HIDDEN];
    for (int i = tid; i < EDGE_FEAT * HIDDEN; i += 256) w1s[i] = W1[i];
    if (tid < HIDDEN) b1s[tid] = b1[tid];
    __syncthreads();
    const int e = (blk - NCHUNK - XCONV_BLKS - ZBLKS) * 256 + tid;
    const float* p = ea + (size_t)e * EDGE_FEAT;
    float a[6];
    #pragma unroll
    for (int f = 0; f < 6; ++f) a[f] = p[f];
    #pragma unroll 4
    for (int k = 0; k < HIDDEN; ++k) {
      float s = b1s[k];
      #pragma unroll
      for (int f = 0; f < 6; ++f) s = fmaf(a[f], w1s[f * HIDDEN + k], s);
      hT[(size_t)k * NUM_EDGES + e] = (f16)fmaxf(s, 0.f);
    }
    hT[(size_t)HIDDEN * NUM_EDGES + e] = (f16)1.f;  // bias row
  }
}

// ---------------------------------------------------------------------------
// Main kernel: grid 512, 2 blocks/CU (8 waves/CU = TLP 2/SIMD), full K.
// Block: 4 waves; wave (mhalf,nhalf) owns 64 edges x 32 out-cols.
// Per iter k:
//   s_waitcnt vmcnt(HT?4:0) lgkmcnt(0); s_barrier   // forces B(k+1) DMA +
//                                                   // h(k) (2 iters old) done;
//                                                   // leaves h(k+1) in flight
//   DMA STAGE B(k+2) -> Bb[k&1]  (overwrites B(k), fully read last iter)
//   capture h slot; issue h(k+2) loads into same slot (static ping-pong)
//   ds_read B(k+1) frags -> reg double buffer (under MFMA)
//   MFMA(k) x16 from regs  [setprio 1]
// ---------------------------------------------------------------------------
template<int HT>
__global__ __launch_bounds__(256, 2) void nnconv_kernel(
    const float* __restrict__ ea, const float* __restrict__ W1,
    const float* __restrict__ b1, const int* __restrict__ senders,
    const int* __restrict__ receivers, const f16* __restrict__ ws_h,
    float* __restrict__ out)
{
  const f16* x_h = ws_h;
  const f16* W2g = ws_h + XH_HALFS;
  const f16* hT  = ws_h + XH_HALFS + W2G_HALFS;
  __shared__ __align__(16) f16 xt[BM][XPAD];     // 18 KB
  __shared__ __align__(16) f16 Bb[2][4096];      // 16 KB  (34 KB total x2/CU)

  const int tid = threadIdx.x;
  const int lane = tid & 63, wid = tid >> 6;
  const int quad = lane >> 4, l15 = lane & 15;
  const int mhalf = wid >> 1, nhalf = wid & 1;
  const int e0 = blockIdx.x * BM;
  const int mbase = mhalf * 64;

  // ---- gather sender x rows (f16) into LDS: 2 threads per row, 64B each
  {
    int r = tid >> 1, half = tid & 1;
    int s = senders[e0 + r];
    const uint4* src = (const uint4*)(x_h + (size_t)s * WIDTH + half * 32);
    uint4* dst = (uint4*)&xt[r][half * 32];
    #pragma unroll
    for (int i = 0; i < 4; ++i) dst[i] = src[i];
  }

  // ---- fallback-only edge_attr rows
  float ear[4][6];
  if (!HT) {
    #pragma unroll
    for (int t = 0; t < 4; ++t) {
      const float* p = ea + (size_t)(e0 + mbase + t * 16 + l15) * EDGE_FEAT;
      #pragma unroll
      for (int f = 0; f < 6; ++f) ear[t][f] = p[f];
    }
  }

  // ---- per-lane B-fragment LDS offsets (swizzled), ki-invariant
  // wave covers n in [nhalf*32, nhalf*32+32): nt 0..1
  int boff[2][2];
  #pragma unroll
  for (int kc = 0; kc < 2; ++kc)
    #pragma unroll
    for (int nt = 0; nt < 2; ++nt) {
      int n = (nhalf * 2 + nt) * 16 + l15;
      int g = kc * 4 + quad;
      boff[kc][nt] = n * 64 + (g ^ (n & 7)) * 8;
    }

  const int hrow = e0 + mbase + l15;
  const int stg_src = wid * 512 + (lane << 3);  // halfs
  const int stg_dst = wid * 512;                // halfs (wave-uniform)

  // ---- prologue: STAGE B(0)->Bb[0], B(1)->Bb[1]; h(0)->hA, h(1)->hB
  gload_lds16(W2g + stg_src, &Bb[0][stg_dst]);
  gload_lds16(W2g + 2048 + stg_src, &Bb[0][stg_dst + 2048]);
  gload_lds16(W2g + 4096 + stg_src, &Bb[1][stg_dst]);
  gload_lds16(W2g + 6144 + stg_src, &Bb[1][stg_dst + 2048]);
  f16 hA[4], hB[4];
  if (HT) {
    #pragma unroll
    for (int t = 0; t < 4; ++t) hA[t] = hT[hrow + t * 16];
    #pragma unroll
    for (int t = 0; t < 4; ++t) hB[t] = hT[(size_t)NUM_EDGES + hrow + t * 16];
  }

  __syncthreads();  // full drain once: xt, Bb[0..1], hA/hB all ready

  // ---- x fragments, held in regs all loop (A: m=l15, k-octet=quad)
  f16x8 xf[4][2];
  #pragma unroll
  for (int t = 0; t < 4; ++t)
    #pragma unroll
    for (int kc = 0; kc < 2; ++kc)
      xf[t][kc] = *(const f16x8*)&xt[mbase + t * 16 + l15][kc * 32 + quad * 8];

  f32x4 acc[4][2];
  #pragma unroll
  for (int t = 0; t < 4; ++t)
    #pragma unroll
    for (int nt = 0; nt < 2; ++nt)
      acc[t][nt] = (f32x4){0.f, 0.f, 0.f, 0.f};

  // ---- READ(0) -> bfA
  f16x8 bfA[2][2], bfB[2][2];
  #pragma unroll
  for (int kc = 0; kc < 2; ++kc)
    #pragma unroll
    for (int nt = 0; nt < 2; ++nt)
      bfA[kc][nt] = *(const f16x8*)&Bb[0][boff[kc][nt]];

#define NN_STEP(K, HS, CUR, NXT, DOREAD)                                      \
  {                                                                           \
    asm volatile("s_waitcnt vmcnt(%0) lgkmcnt(0)\n\ts_barrier"                \
                 :: "i"(HT ? 4 : 0) : "memory");                              \
    __builtin_amdgcn_sched_barrier(0);                                        \
    const int c2_ = ((K) + 2 <= 128) ? (K) + 2 : 128;                         \
    {                                                                         \
      const f16* src_ = W2g + (size_t)c2_ * 4096 + stg_src;                   \
      f16* dst_ = &Bb[(K) & 1][stg_dst];                                      \
      gload_lds16(src_, dst_);                                                \
      gload_lds16(src_ + 2048, dst_ + 2048);                                  \
    }                                                                         \
    __builtin_amdgcn_sched_barrier(0); /* DMA issued before h loads */        \
    f16 hv_[4];                                                               \
    if (HT) {                                                                 \
      _Pragma("unroll") for (int t = 0; t < 4; ++t) hv_[t] = HS[t];           \
      const f16* hp_ = hT + (size_t)c2_ * NUM_EDGES + hrow;                   \
      HS[0] = hp_[0]; HS[1] = hp_[16]; HS[2] = hp_[32]; HS[3] = hp_[48];      \
      __builtin_amdgcn_sched_barrier(0); /* h loads pinned here */            \
    } else {                                                                  \
      if ((K) < HIDDEN) {                                                     \
        float b1c_ = b1[(K)];                                                 \
        float w1c_[6];                                                        \
        _Pragma("unroll") for (int f = 0; f < 6; ++f)                         \
          w1c_[f] = W1[f * HIDDEN + (K)];                                     \
        _Pragma("unroll") for (int t = 0; t < 4; ++t) {                       \
          float s_ = b1c_;                                                    \
          _Pragma("unroll") for (int f = 0; f < 6; ++f)                       \
            s_ = fmaf(ear[t][f], w1c_[f], s_);                                \
          hv_[t] = (f16)fmaxf(s_, 0.f);                                       \
        }                                                                     \
      } else {                                                                \
        _Pragma("unroll") for (int t = 0; t < 4; ++t) hv_[t] = (f16)1.f;      \
      }                                                                       \
    }                                                                         \
    if (DOREAD) {                                                             \
      f16* rb_ = &Bb[((K) + 1) & 1][0];                                       \
      _Pragma("unroll") for (int kc = 0; kc < 2; ++kc)                        \
        _Pragma("unroll") for (int nt = 0; nt < 2; ++nt)                      \
          NXT[kc][nt] = *(const f16x8*)&rb_[boff[kc][nt]];                    \
    }                                                                         \
    __builtin_amdgcn_s_setprio(1);                                            \
    _Pragma("unroll") for (int t = 0; t < 4; ++t) {                           \
      f16x8 sa0_ = xf[t][0] * hv_[t];                                         \
      f16x8 sa1_ = xf[t][1] * hv_[t];                                         \
      _Pragma("unroll") for (int nt = 0; nt < 2; ++nt) {                      \
        acc[t][nt] = __builtin_amdgcn_mfma_f32_16x16x32_f16(                  \
            sa0_, CUR[0][nt], acc[t][nt], 0, 0, 0);                           \
        acc[t][nt] = __builtin_amdgcn_mfma_f32_16x16x32_f16(                  \
            sa1_, CUR[1][nt], acc[t][nt], 0, 0, 0);                           \
      }                                                                       \
    }                                                                         \
    __builtin_amdgcn_s_setprio(0);                                            \
  }

  #pragma unroll 1
  for (int kb = 0; kb < 64; ++kb) {
    NN_STEP(2 * kb,     hA, bfA, bfB, 1);
    NN_STEP(2 * kb + 1, hB, bfB, bfA, 1);
  }
  NN_STEP(128, hA, bfA, bfB, 0);
#undef NN_STEP

  // drain remaining DMA / h loads before exit + epilogue
  asm volatile("s_waitcnt vmcnt(0)" ::: "memory");

  // ---- epilogue: C row = quad*4 + reg, col = l15; scatter-add (full sums)
  #pragma unroll
  for (int t = 0; t < 4; ++t) {
    int ebase = e0 + mbase + t * 16 + quad * 4;
    int rc[4];
    #pragma unroll
    for (int r = 0; r < 4; ++r) rc[r] = receivers[ebase + r];
    #pragma unroll
    for (int nt = 0; nt < 2; ++nt) {
      int v = (nhalf * 2 + nt) * 16 + l15;
      #pragma unroll
      for (int r = 0; r < 4; ++r)
        atomicAdd(out + (size_t)rc[r] * WIDTH + v, acc[t][nt][r]);
    }
  }
}

extern "C" void kernel_launch(void* const* d_in, const int* in_sizes, int n_in,
                              void* d_out, int out_size, void* d_ws, size_t ws_size,
                              hipStream_t stream) {
  const float* x  = (const float*)d_in[0];
  const float* ea = (const float*)d_in[1];
  const float* W1 = (const float*)d_in[2];
  const float* b1 = (const float*)d_in[3];
  const float* W2 = (const float*)d_in[4];
  const float* b2 = (const float*)d_in[5];
  const int* snd  = (const int*)d_in[6];
  const int* rcv  = (const int*)d_in[7];
  float* out = (float*)d_out;
  f16* wsh = (f16*)d_ws;

  const size_t need = ((size_t)XH_HALFS + W2G_HALFS + HT_HALFS) * sizeof(f16);
  const int use_ht = (ws_size >= need) ? 1 : 0;

  const int prep_grid = NCHUNK + XCONV_BLKS + ZBLKS + (use_ht ? HBLKS : 0);
  prep_kernel<<<prep_grid, 256, 0, stream>>>(x, W2, b2, ea, W1, b1, wsh, out, use_ht);
  if (use_ht)
    nnconv_kernel<1><<<NUM_EDGES / BM, 256, 0, stream>>>(ea, W1, b1, snd, rcv, wsh, out);
  else
    nnconv_kernel<0><<<NUM_EDGES / BM, 256, 0, stream>>>(ea, W1, b1, snd, rcv, wsh, out);
}

// Round 5
// 147.015 us; speedup vs baseline: 1.1989x; 1.1989x over previous
//
#include <hip/hip_runtime.h>
#include <stdint.h>

typedef _Float16 f16;
typedef f16 f16x8 __attribute__((ext_vector_type(8)));
typedef float f32x4 __attribute__((ext_vector_type(4)));

#define NUM_NODES 20000
#define NUM_EDGES 65536
#define WIDTH 64
#define EDGE_FEAT 6
#define HIDDEN 128
#define BM 256            // edges per workgroup (full-K, grid 256, 512 thr)
#define PADCH 132         // 128 h-chunks + 1 bias chunk + 3 zero pads
#define XPAD 72           // x-tile row stride in halfs

#define XH_HALFS (NUM_NODES * WIDTH)   // 1,280,000 halfs for x in f16
#define XCONV_BLKS 625                 // 625 * 2048 halfs = 1,280,000 exactly
#define W2G_HALFS (PADCH * 4096)       // 540,672 halfs
#define OUT_FLOATS (NUM_NODES * WIDTH) // 1,280,000
#define ZBLKS 313                      // 313 * 4096 >= OUT_FLOATS

// direct global->LDS DMA, 16B per lane. lds dest wave-uniform; HW adds lane*16.
__device__ __forceinline__ void gload_lds16(const f16* g, f16* l) {
  __builtin_amdgcn_global_load_lds(
      (const __attribute__((address_space(1))) unsigned int*)g,
      (__attribute__((address_space(3))) unsigned int*)l, 16, 0, 0);
}

// ---------------------------------------------------------------------------
// Prep: (a) W2g: 132 chunks of [64n x 64k] f16, transposed + XOR-granule
//       swizzled (chunk 128 = bias b2, 129..131 = zeros); (b) x fp32->f16;
//       (c) zero `out`.
// ---------------------------------------------------------------------------
__global__ __launch_bounds__(256) void prep_kernel(
    const float* __restrict__ x, const float* __restrict__ W2,
    const float* __restrict__ b2, f16* __restrict__ ws_h,
    float* __restrict__ out)
{
  f16* x_h = ws_h;
  f16* W2g = ws_h + XH_HALFS;
  const int blk = blockIdx.x, tid = threadIdx.x;

  if (blk < PADCH) {
    const int ki = blk;
    if (ki > HIDDEN) {  // zero pad chunks 129..131
      f16x8 z;
      #pragma unroll
      for (int u = 0; u < 8; ++u) z[u] = (f16)0.f;
      *(f16x8*)&W2g[(size_t)ki * 4096 + tid * 16] = z;
      *(f16x8*)&W2g[(size_t)ki * 4096 + tid * 16 + 8] = z;
      return;
    }
    __shared__ float row[4096];
    const float* srcrow;
    if (ki < HIDDEN) {
      const float4* src = (const float4*)(W2 + (size_t)ki * 4096);
      #pragma unroll
      for (int i = 0; i < 4; ++i) {
        float4 v = src[tid + 256 * i];
        *(float4*)&row[(tid + 256 * i) * 4] = v;
      }
      __syncthreads();
      srcrow = row;
    } else {
      srcrow = b2;  // bias chunk
    }
    const int obase = tid * 16;
    f16x8 outv0, outv1;
    #pragma unroll
    for (int u = 0; u < 8; ++u) {
      int o = obase + u;
      int n = o >> 6, pg = (o >> 3) & 7, j = o & 7;
      int k = (pg ^ (n & 7)) * 8 + j;
      outv0[u] = (f16)srcrow[k * 64 + n];
    }
    #pragma unroll
    for (int u = 0; u < 8; ++u) {
      int o = obase + 8 + u;
      int n = o >> 6, pg = (o >> 3) & 7, j = o & 7;
      int k = (pg ^ (n & 7)) * 8 + j;
      outv1[u] = (f16)srcrow[k * 64 + n];
    }
    *(f16x8*)&W2g[(size_t)ki * 4096 + obase] = outv0;
    *(f16x8*)&W2g[(size_t)ki * 4096 + obase + 8] = outv1;
  } else if (blk < PADCH + XCONV_BLKS) {
    int idx = (blk - PADCH) * 2048 + tid * 8;
    if (idx + 8 <= XH_HALFS) {
      float4 a = *(const float4*)(x + idx);
      float4 b = *(const float4*)(x + idx + 4);
      f16x8 hv;
      hv[0] = (f16)a.x; hv[1] = (f16)a.y; hv[2] = (f16)a.z; hv[3] = (f16)a.w;
      hv[4] = (f16)b.x; hv[5] = (f16)b.y; hv[6] = (f16)b.z; hv[7] = (f16)b.w;
      *(f16x8*)&x_h[idx] = hv;
    }
  } else {
    int base = (blk - PADCH - XCONV_BLKS) * 4096 + tid * 16;
    float4 z = {0.f, 0.f, 0.f, 0.f};
    #pragma unroll
    for (int i = 0; i < 4; ++i) {
      int idx = base + i * 4;
      if (idx + 4 <= OUT_FLOATS) *(float4*)(out + idx) = z;
    }
  }
}

// ---------------------------------------------------------------------------
// Main kernel: grid 256, 512 threads (8 waves), 1 block/CU, full K.
// Wave (mquad, nhalf) owns 64 edges x 32 out-cols; 16 MFMA per chunk.
// Barrier-amortized pipeline: G=4 chunks (32 KB) staged per sync in a
// 2-group LDS ring. Per group (~2500+ cyc of MFMA):
//   s_waitcnt vmcnt(0) lgkmcnt(0); s_barrier   // free: DMAs are 1 group old
//   STAGE(group g+1) -> ring[(g+1)&1]           // 4 DMA instrs per wave
//   compute 4 chunks: h recomputed in VALU (overlaps MFMA), B frags
//   ds_read'd with 1-chunk register ping-pong under MFMA.
// Tail: chunk 128 (bias, h==1) -> acc += xf * B128.
// ---------------------------------------------------------------------------
__global__ __launch_bounds__(512, 1) void nnconv_kernel(
    const float* __restrict__ ea, const float* __restrict__ W1,
    const float* __restrict__ b1, const int* __restrict__ senders,
    const int* __restrict__ receivers, const f16* __restrict__ ws_h,
    float* __restrict__ out)
{
  const f16* x_h = ws_h;
  const f16* W2g = ws_h + XH_HALFS;
  __shared__ __align__(16) f16 xt[BM][XPAD];     // 36 KB
  __shared__ __align__(16) f16 Bring[2 * 16384]; // 64 KB (2 groups x 4 chunks)

  const int tid = threadIdx.x;
  const int lane = tid & 63, wid = tid >> 6;
  const int quad = lane >> 4, l15 = lane & 15;
  const int mquad = wid >> 1, nhalf = wid & 1;
  const int e0 = blockIdx.x * BM;
  const int mbase = mquad * 64;
  f16* BrF = &Bring[0];

  // ---- stage group 0 first (longest flight time)
#define STAGE(GIDX, GP)                                                       \
  {                                                                           \
    _Pragma("unroll") for (int i_ = 0; i_ < 4; ++i_) {                        \
      int slice_ = wid + 8 * i_;                                              \
      gload_lds16(W2g + (size_t)(GIDX) * 16384 + slice_ * 512 + (lane << 3),  \
                  BrF + (GP) * 16384 + slice_ * 512);                         \
    }                                                                         \
  }
  STAGE(0, 0);

  // ---- gather sender x rows (f16) into LDS: 2 threads per row, 64B each
  {
    int r = tid >> 1, half = tid & 1;
    int s = senders[e0 + r];
    const uint4* src = (const uint4*)(x_h + (size_t)s * WIDTH + half * 32);
    uint4* dst = (uint4*)&xt[r][half * 32];
    #pragma unroll
    for (int i = 0; i < 4; ++i) dst[i] = src[i];
  }

  // ---- per-lane edge_attr rows for in-loop h recompute (4 m-subtiles)
  float ear[4][6];
  #pragma unroll
  for (int t = 0; t < 4; ++t) {
    const float* p = ea + (size_t)(e0 + mbase + t * 16 + l15) * EDGE_FEAT;
    #pragma unroll
    for (int f = 0; f < 6; ++f) ear[t][f] = p[f];
  }

  // ---- per-lane B-fragment LDS offsets within a chunk (swizzled)
  int boff[2][2];
  #pragma unroll
  for (int kc = 0; kc < 2; ++kc)
    #pragma unroll
    for (int nt = 0; nt < 2; ++nt) {
      int n = (nhalf * 2 + nt) * 16 + l15;
      int g = kc * 4 + quad;
      boff[kc][nt] = n * 64 + (g ^ (n & 7)) * 8;
    }

  __syncthreads();  // xt + group 0 staged (full drain, once)

  // ---- x fragments, held in regs all loop (A: m=l15, k-octet=quad)
  f16x8 xf[4][2];
  #pragma unroll
  for (int t = 0; t < 4; ++t)
    #pragma unroll
    for (int kc = 0; kc < 2; ++kc)
      xf[t][kc] = *(const f16x8*)&xt[mbase + t * 16 + l15][kc * 32 + quad * 8];

  f32x4 acc[4][2];
  #pragma unroll
  for (int t = 0; t < 4; ++t)
    #pragma unroll
    for (int nt = 0; nt < 2; ++nt)
      acc[t][nt] = (f32x4){0.f, 0.f, 0.f, 0.f};

#define RD(DST, CBASE)                                                        \
  _Pragma("unroll") for (int kc = 0; kc < 2; ++kc)                            \
    _Pragma("unroll") for (int nt = 0; nt < 2; ++nt)                          \
      DST[kc][nt] = *(const f16x8*)&(CBASE)[boff[kc][nt]];

#define MM(BF, HV)                                                            \
  __builtin_amdgcn_s_setprio(1);                                              \
  _Pragma("unroll") for (int t = 0; t < 4; ++t) {                             \
    f16x8 sa0_ = xf[t][0] * HV[t];                                            \
    f16x8 sa1_ = xf[t][1] * HV[t];                                            \
    _Pragma("unroll") for (int nt = 0; nt < 2; ++nt) {                        \
      acc[t][nt] = __builtin_amdgcn_mfma_f32_16x16x32_f16(                    \
          sa0_, BF[0][nt], acc[t][nt], 0, 0, 0);                              \
      acc[t][nt] = __builtin_amdgcn_mfma_f32_16x16x32_f16(                    \
          sa1_, BF[1][nt], acc[t][nt], 0, 0, 0);                              \
    }                                                                         \
  }                                                                           \
  __builtin_amdgcn_s_setprio(0);

#define HCOMP(KI, HV)                                                         \
  {                                                                           \
    float b1c_ = b1[(KI)];                                                    \
    float w1c_[6];                                                            \
    _Pragma("unroll") for (int f = 0; f < 6; ++f)                             \
      w1c_[f] = W1[f * HIDDEN + (KI)];                                        \
    _Pragma("unroll") for (int t = 0; t < 4; ++t) {                           \
      float s_ = b1c_;                                                        \
      _Pragma("unroll") for (int f = 0; f < 6; ++f)                           \
        s_ = fmaf(ear[t][f], w1c_[f], s_);                                    \
      HV[t] = (f16)fmaxf(s_, 0.f);                                            \
    }                                                                         \
  }

  // ---- main loop: 32 groups of 4 chunks (ki 0..127)
  #pragma unroll 1
  for (int g = 0; g < 32; ++g) {
    // all outstanding DMAs are >= 1 group (~2500 cyc) old -> near-free wait
    asm volatile("s_waitcnt vmcnt(0) lgkmcnt(0)\n\ts_barrier" ::: "memory");
    __builtin_amdgcn_sched_barrier(0);
    STAGE(g + 1, (g + 1) & 1);   // g=31 stages chunks 128..131 (pad-safe)
    __builtin_amdgcn_sched_barrier(0);

    f16* gb = BrF + (g & 1) * 16384;
    const int kb = g * 4;
    f16 h0[4], h1[4], h2[4], h3[4];
    HCOMP(kb + 0, h0);
    HCOMP(kb + 1, h1);
    HCOMP(kb + 2, h2);
    HCOMP(kb + 3, h3);

    f16x8 bfP[2][2], bfQ[2][2];
    RD(bfP, gb);
    RD(bfQ, gb + 4096);
    MM(bfP, h0);
    RD(bfP, gb + 8192);
    MM(bfQ, h1);
    RD(bfQ, gb + 12288);
    MM(bfP, h2);
    MM(bfQ, h3);
  }

  // ---- tail: chunk 128 (bias row, h == 1): acc += xf * B128
  asm volatile("s_waitcnt vmcnt(0) lgkmcnt(0)\n\ts_barrier" ::: "memory");
  __builtin_amdgcn_sched_barrier(0);
  {
    f16x8 bfP[2][2];
    RD(bfP, BrF);  // group 32 -> parity 0, chunk slot 0 = ki 128
    __builtin_amdgcn_s_setprio(1);
    #pragma unroll
    for (int t = 0; t < 4; ++t)
      #pragma unroll
      for (int nt = 0; nt < 2; ++nt) {
        acc[t][nt] = __builtin_amdgcn_mfma_f32_16x16x32_f16(
            xf[t][0], bfP[0][nt], acc[t][nt], 0, 0, 0);
        acc[t][nt] = __builtin_amdgcn_mfma_f32_16x16x32_f16(
            xf[t][1], bfP[1][nt], acc[t][nt], 0, 0, 0);
      }
    __builtin_amdgcn_s_setprio(0);
  }
#undef STAGE
#undef RD
#undef MM
#undef HCOMP

  // ---- epilogue: C row = quad*4 + reg, col = l15; scatter-add (full sums)
  #pragma unroll
  for (int t = 0; t < 4; ++t) {
    int ebase = e0 + mbase + t * 16 + quad * 4;
    int rc[4];
    #pragma unroll
    for (int r = 0; r < 4; ++r) rc[r] = receivers[ebase + r];
    #pragma unroll
    for (int nt = 0; nt < 2; ++nt) {
      int v = (nhalf * 2 + nt) * 16 + l15;
      #pragma unroll
      for (int r = 0; r < 4; ++r)
        atomicAdd(out + (size_t)rc[r] * WIDTH + v, acc[t][nt][r]);
    }
  }
}

extern "C" void kernel_launch(void* const* d_in, const int* in_sizes, int n_in,
                              void* d_out, int out_size, void* d_ws, size_t ws_size,
                              hipStream_t stream) {
  const float* x  = (const float*)d_in[0];
  const float* ea = (const float*)d_in[1];
  const float* W1 = (const float*)d_in[2];
  const float* b1 = (const float*)d_in[3];
  const float* W2 = (const float*)d_in[4];
  const float* b2 = (const float*)d_in[5];
  const int* snd  = (const int*)d_in[6];
  const int* rcv  = (const int*)d_in[7];
  float* out = (float*)d_out;
  f16* wsh = (f16*)d_ws;

  const int prep_grid = PADCH + XCONV_BLKS + ZBLKS;
  prep_kernel<<<prep_grid, 256, 0, stream>>>(x, W2, b2, wsh, out);
  nnconv_kernel<<<NUM_EDGES / BM, 512, 0, stream>>>(ea, W1, b1, snd, rcv, wsh, out);
}